// Round 3
// baseline (631.656 us; speedup 1.0000x reference)
//
#include <hip/hip_runtime.h>
#include <math.h>

#define B_IMG 16
#define N_PROP 2048
#define C_CLS 3
#define K_OUT 100
#define NTHREADS 1024
#define NWAVES (NTHREADS / 64)
#define NBLK64 (N_PROP / 64)

__device__ __forceinline__ unsigned long long shfl_xor_u64(unsigned long long v, int lx) {
    unsigned int lo = (unsigned int)__shfl_xor((int)(unsigned int)(v & 0xffffffffull), lx, 64);
    unsigned int hi = (unsigned int)__shfl_xor((int)(unsigned int)(v >> 32), lx, 64);
    return ((unsigned long long)hi << 32) | (unsigned long long)lo;
}
__device__ __forceinline__ float readlane_f(float v, int l) {
    return __int_as_float(__builtin_amdgcn_readlane(__float_as_int(v), l));
}
__device__ __forceinline__ unsigned long long readlane_u64(unsigned long long v, int l) {
    unsigned int lo = (unsigned int)__builtin_amdgcn_readlane((int)(unsigned int)(v & 0xffffffffull), l);
    unsigned int hi = (unsigned int)__builtin_amdgcn_readlane((int)(unsigned int)(v >> 32), l);
    return ((unsigned long long)hi << 32) | (unsigned long long)lo;
}
// Exact replacement for: RN(inter / max(uni,1e-8f)) > 0.5f  (bit-equivalent)
__device__ __forceinline__ bool iou_gt_half(float inter, float uni) {
    double b = (double)fmaxf(uni, 1e-8f);
    return (double)inter * 2.0 > b * 0x1.000001p0;
}
__device__ __forceinline__ float parse_imgf(int raw) {
    return (raw > 0 && raw < 1000000) ? (float)raw : __int_as_float(raw);
}

// ---------------- staged kernel for phase ablation ----------------
// STAGE: 1=decode only, 2=+sort, 3=+gather+NMS, 4=full pipeline -> out.
// REP: repeat count so each diagnostic dispatch exceeds the 40us top-5 floor.
// An asm-opaque zero is XORed into the load index each rep so the compiler
// cannot CSE/hoist the decode across reps (rule: ablation-via-skip DCEs
// upstream-dead ops -- here we force liveness via ws stores + opaque index).
template <int STAGE, int REP>
__global__ __launch_bounds__(NTHREADS)
void roiheads_stage(const float* __restrict__ class_logit,
                    const float* __restrict__ box_reg,
                    const float* __restrict__ proposal,
                    const int* __restrict__ image_shape_p,
                    float* __restrict__ out,
                    unsigned long long* __restrict__ dkey,   // per-stage ws region
                    float2* __restrict__ dbox)               // per-stage ws region
{
#pragma clang fp contract(off)
    __shared__ unsigned long long skey[N_PROP];     // 16 KB sort keys
    __shared__ float blo_n[N_PROP], bhi_n[N_PROP];  // boxes, original index order
    __shared__ float slo[N_PROP], shi[N_PROP];      // boxes in sorted order
    __shared__ unsigned char keep[N_PROP];
    __shared__ unsigned short alv[2][N_PROP];       // alive (undecided) sorted positions
    __shared__ float clo[64], chi[64];              // current chunk's kept boxes
    __shared__ unsigned long long sup[64];          // chunk suppression matrix rows
    __shared__ unsigned long long kmask[NBLK64];
    __shared__ int wsum[NWAVES];
    __shared__ int sh_nvalid;

    const int tid = threadIdx.x;
    const int lane = tid & 63;
    const int wid = tid >> 6;
    const int img = blockIdx.x >> 1;
    const int cls = blockIdx.x & 1;                 // fg class index-1
    const float imgf = parse_imgf(image_shape_p[0]);
    const size_t wbase = (size_t)blockIdx.x * N_PROP;

    const int p0 = (wid << 7) | (lane << 1);        // == 2*tid
    const int p1 = p0 | 1;
    const unsigned long long below = (1ull << lane) - 1ull;

    for (int rep = 0; rep < REP; ++rep) {
        __syncthreads();                            // guard LDS reuse across reps
        unsigned int kz;
        asm volatile("v_mov_b32 %0, 0" : "=v"(kz)); // opaque 0: defeats cross-rep CSE
        if (tid == 0) sh_nvalid = 0;

        // ---- decode items p0,p1 into register sort keys (fp sequence = reference) ----
        unsigned long long r0 = 0, r1 = 0;
#pragma unroll
        for (int e = 0; e < 2; ++e) {
            const int n = p0 + e;
            const int nx = n ^ (int)kz;             // == n, but opaque
            const size_t g = (size_t)img * N_PROP + nx;
            const float* lg = class_logit + g * C_CLS;
            float l0 = lg[0], l1 = lg[1], l2 = lg[2];
            float mx = fmaxf(l0, fmaxf(l1, l2));
            float e0 = (float)exp((double)(l0 - mx));
            float e1 = (float)exp((double)(l1 - mx));
            float e2 = (float)exp((double)(l2 - mx));
            float denom = (e0 + e1) + e2;
            float score = ((cls == 0) ? e1 : e2) / denom;

            const float* dr = box_reg + g * (2 * C_CLS) + 2 * (cls + 1);
            float dx = dr[0];
            float dw = fminf(dr[1], 4.0f);
            const float* pp = proposal + g * 2;
            float pA = pp[0], pB = pp[1];
            float w = pB - pA;
            float ctr = pA + 0.5f * w;
            float tt = dx * w;
            float pc = tt + ctr;
            float pw = (float)exp((double)dw) * w;
            float half = 0.5f * pw;
            float lo = pc - half;
            float hi = pc + half;
            lo = fminf(fmaxf(lo, 0.0f), imgf);
            hi = fminf(fmaxf(hi, 0.0f), imgf);
            bool valid = ((hi - lo) >= 10.0f) && (score >= 0.05f);
            float ms = valid ? score : -1e9f;
            blo_n[n] = lo;
            bhi_n[n] = hi;
            if constexpr (STAGE == 1) dbox[wbase + n] = make_float2(lo, hi);
            unsigned int uu = __float_as_uint(ms);
            unsigned int enc = (uu & 0x80000000u) ? ~uu : (uu | 0x80000000u);
            unsigned long long key = ((unsigned long long)enc << 32) |
                                     (unsigned long long)(0xFFFFFFFFu - (unsigned int)n);
            if (e == 0) r0 = key; else r1 = key;
        }
        if constexpr (STAGE == 1) {
            dkey[wbase + p0] = r0; dkey[wbase + p1] = r1;
            continue;
        }

        // ---- full hybrid reg/LDS bitonic sort over 2048 (descending) ----
        auto pass_inreg = [&](int k, int j) {
            if (j == 1) {
                bool desc = ((p0 & k) == 0);
                bool sw = desc ? (r0 < r1) : (r0 > r1);
                if (sw) { unsigned long long t = r0; r0 = r1; r1 = t; }
            } else {
                int lx = j >> 1;
                unsigned long long o0 = shfl_xor_u64(r0, lx);
                unsigned long long o1 = shfl_xor_u64(r1, lx);
                bool desc = ((p0 & k) == 0);
                bool lower = ((p0 & j) == 0);
                bool takeMax = (lower == desc);
                r0 = takeMax ? (r0 > o0 ? r0 : o0) : (r0 < o0 ? r0 : o0);
                r1 = takeMax ? (r1 > o1 ? r1 : o1) : (r1 < o1 ? r1 : o1);
            }
        };

        for (int k = 2; k <= 128; k <<= 1)
            for (int j = k >> 1; j >= 1; j >>= 1)
                pass_inreg(k, j);

        for (int k = 256; k <= N_PROP; k <<= 1) {
            skey[p0] = r0; skey[p1] = r1;
            __syncthreads();
            for (int j = k >> 1; j >= 128; j >>= 1) {
                int i = ((tid & ~(j - 1)) << 1) | (tid & (j - 1));
                int part = i | j;
                unsigned long long a = skey[i], b = skey[part];
                bool desc_blk = ((i & k) == 0);
                bool sw = desc_blk ? (a < b) : (a > b);
                if (sw) { skey[i] = b; skey[part] = a; }
                __syncthreads();
            }
            r0 = skey[p0]; r1 = skey[p1];
            for (int j = 64; j >= 1; j >>= 1)
                pass_inreg(k, j);
        }
        skey[p0] = r0; skey[p1] = r1;
        __syncthreads();

        if constexpr (STAGE == 2) {
            dkey[wbase + p0] = r0; dkey[wbase + p1] = r1;
            dbox[wbase + p0] = make_float2(blo_n[p0], bhi_n[p0]);
            dbox[wbase + p1] = make_float2(blo_n[p1], bhi_n[p1]);
            continue;
        }

        // ---- gather sorted boxes from LDS, count valid, init alive list ----
        for (int i = tid; i < N_PROP; i += NTHREADS) {
            unsigned long long kk = skey[i];
            unsigned int e = (unsigned int)(kk >> 32);
            unsigned int sb = (e & 0x80000000u) ? (e & 0x7FFFFFFFu) : ~e;
            float s = __uint_as_float(sb);
            unsigned int n = 0xFFFFFFFFu - (unsigned int)(kk & 0xFFFFFFFFull);
            slo[i] = blo_n[n];
            shi[i] = bhi_n[n];
            keep[i] = 0;
            bool v = (s > -5e8f);
            unsigned long long mb = __ballot(v);
            if (lane == 0) atomicAdd(&sh_nvalid, __popcll(mb));
            alv[0][i] = (unsigned short)i;
        }
        __syncthreads();

        int na = sh_nvalid;
        int cur = 0;
        int tk = 0;

        // ---- greedy NMS: 64-candidate chunks (round-1 verified version) ----
        while (na > 0) {
            const int m = (na < 64) ? na : 64;

            unsigned short cp = alv[cur][lane];
            bool cin = (lane < m);
            float qloc = cin ? slo[cp] : 0.0f;
            float qhic = cin ? shi[cp] : 0.0f;

#pragma unroll
            for (int rr4 = 0; rr4 < 4; ++rr4) {
                int rr = (wid << 2) | rr4;
                unsigned long long row = 0;
                if (rr < m) {
                    unsigned short rp = alv[cur][rr];
                    float rlo = slo[rp], rhi = shi[rp];
                    float inter = fmaxf(fminf(rhi, qhic) - fmaxf(rlo, qloc), 0.0f);
                    float uni = (rhi - rlo) + (qhic - qloc) - inter;
                    bool kill = cin && (lane > rr) && iou_gt_half(inter, uni);
                    row = __ballot(kill);
                }
                if (lane == 0) sup[rr] = row;
            }
            __syncthreads();

            unsigned long long rw = sup[lane];
            unsigned long long A = (m >= 64) ? ~0ull : ((1ull << m) - 1ull);
            unsigned long long kept = 0;
            while (A) {
                int c = __builtin_ctzll(A);
                kept |= (1ull << c);
                A &= ~(readlane_u64(rw, c) | (1ull << c));
            }
            const int cnt = __popcll(kept);

            if (wid == 0) {
                bool alive = cin && ((kept >> lane) & 1ull);
                if (alive) {
                    keep[cp] = 1;
                    int rank = __popcll(kept & below);
                    clo[rank] = qloc; chi[rank] = qhic;
                }
            }
            __syncthreads();
            tk += cnt;
            if (tk >= K_OUT) break;

            float klo = 0.0f, khi = 0.0f;
            if (lane < cnt) { klo = clo[lane]; khi = chi[lane]; }
            int base2 = 0;
            for (int start = 64; start < na; start += NTHREADS) {
                int t2 = start + tid;
                unsigned short qq = 0;
                bool surv = false;
                if (t2 < na) {
                    qq = alv[cur][t2];
                    float qlo = slo[qq], qhi = shi[qq];
                    float qw = qhi - qlo;
                    bool dead = false;
                    for (int r = 0; r < cnt; ++r) {
                        float cl = readlane_f(klo, r);
                        float ch = readlane_f(khi, r);
                        float inter = fmaxf(fminf(qhi, ch) - fmaxf(qlo, cl), 0.0f);
                        float uni = qw + (ch - cl) - inter;
                        dead |= iou_gt_half(inter, uni);
                    }
                    surv = !dead;
                }
                unsigned long long mb = __ballot(surv);
                if (lane == 0) wsum[wid] = __popcll(mb);
                __syncthreads();
                int off2 = base2, tot = base2;
                for (int w2 = 0; w2 < NWAVES; ++w2) {
                    int c2 = wsum[w2];
                    if (w2 < wid) off2 += c2;
                    tot += c2;
                }
                if (surv) alv[cur ^ 1][off2 + __popcll(mb & below)] = qq;
                base2 = tot;
                __syncthreads();
            }
            na = base2;
            cur ^= 1;
        }

        // ---- kmask build (needed by stage 3 store and stage 4 output) ----
        for (int blk = wid; blk < NBLK64; blk += NWAVES) {
            bool kk = keep[blk * 64 + lane] != 0;
            unsigned long long mb = __ballot(kk);
            if (lane == 0) kmask[blk] = mb;
        }
        __syncthreads();

        if constexpr (STAGE == 3) {
            if (tid < NBLK64) dkey[wbase + tid] = kmask[tid];
            if (tid == 0) dkey[wbase + NBLK64] =
                ((unsigned long long)(unsigned)tk << 32) | (unsigned)na;
            continue;
        }

        // ---- top-K fill (reproduces lax.top_k tie-breaking exactly) ----
        {
            float* outp = out + (((size_t)img * 2 + cls) * K_OUT) * 3;
            for (int blk = wid; blk < NBLK64; blk += NWAVES) {
                int kc = 0, nc = 0, nk = 0;
                for (int b = 0; b < NBLK64; ++b) {
                    int pc = __popcll(kmask[b]);
                    nk += pc;
                    if (b < blk) { kc += pc; nc += 64 - pc; }
                }
                if (kc >= K_OUT && nk + nc >= K_OUT && nc >= K_OUT) continue;
                int p = blk * 64 + lane;
                unsigned long long mb = kmask[blk];
                bool k = (mb >> lane) & 1ull;
                int rk = kc + __popcll(mb & below);
                int rn = nc + __popcll((~mb) & below);
                if (k) {
                    if (rk < K_OUT) {
                        unsigned long long kk2 = skey[p];
                        unsigned int e = (unsigned int)(kk2 >> 32);
                        unsigned int sb = (e & 0x80000000u) ? (e & 0x7FFFFFFFu) : ~e;
                        outp[rk * 3 + 0] = slo[p];
                        outp[rk * 3 + 1] = shi[p];
                        outp[rk * 3 + 2] = __uint_as_float(sb);
                    }
                } else {
                    int oi = nk + rn;
                    if (oi < K_OUT) {
                        outp[oi * 3 + 0] = slo[p];
                        outp[oi * 3 + 1] = shi[p];
                        outp[oi * 3 + 2] = -1e9f;
                    }
                }
            }
        }
    }
}

extern "C" void kernel_launch(void* const* d_in, const int* in_sizes, int n_in,
                              void* d_out, int out_size, void* d_ws, size_t ws_size,
                              hipStream_t stream) {
    const float* class_logit = (const float*)d_in[0];
    const float* box_reg     = (const float*)d_in[1];
    const float* prop        = (const float*)d_in[2];
    const int*   image_shape = (const int*)d_in[3];
    float* out = (float*)d_out;
    char* ws = (char*)d_ws;
    const size_t MB = 1024 * 1024;

    // diagnostic ablation dispatches (results -> workspace, kept live)
    roiheads_stage<1, 32><<<dim3(B_IMG * 2), dim3(NTHREADS), 0, stream>>>(
        class_logit, box_reg, prop, image_shape, out,
        (unsigned long long*)(ws + 0 * MB), (float2*)(ws + 1 * MB));
    roiheads_stage<2, 16><<<dim3(B_IMG * 2), dim3(NTHREADS), 0, stream>>>(
        class_logit, box_reg, prop, image_shape, out,
        (unsigned long long*)(ws + 2 * MB), (float2*)(ws + 3 * MB));
    roiheads_stage<3, 6><<<dim3(B_IMG * 2), dim3(NTHREADS), 0, stream>>>(
        class_logit, box_reg, prop, image_shape, out,
        (unsigned long long*)(ws + 4 * MB), (float2*)(ws + 5 * MB));
    // the real kernel (round-1 64-chunk version), writes the checked output
    roiheads_stage<4, 1><<<dim3(B_IMG * 2), dim3(NTHREADS), 0, stream>>>(
        class_logit, box_reg, prop, image_shape, out,
        (unsigned long long*)(ws + 6 * MB), (float2*)(ws + 7 * MB));
}

// Round 4
// 263.019 us; speedup vs baseline: 2.4016x; 2.4016x over previous
//
#include <hip/hip_runtime.h>
#include <math.h>

#define B_IMG 16
#define N_PROP 2048
#define C_CLS 3
#define K_OUT 100
#define NTHREADS 1024
#define NWAVES (NTHREADS / 64)
#define NBLK64 (N_PROP / 64)
#define KEPT_MAX 192                       // tk<100 at chunk start + <=64 in-chunk

// Phase budget from R3 ablation (per block): decode ~3us, sort ~12.7us,
// NMS+gather ~24.5us, topK ~1.5us. This version replaces the barrier-heavy
// compaction NMS with a zero-barrier wave0 serial-chunk greedy.

__device__ __forceinline__ unsigned long long shfl_xor_u64(unsigned long long v, int lx) {
    unsigned int lo = (unsigned int)__shfl_xor((int)(unsigned int)(v & 0xffffffffull), lx, 64);
    unsigned int hi = (unsigned int)__shfl_xor((int)(unsigned int)(v >> 32), lx, 64);
    return ((unsigned long long)hi << 32) | (unsigned long long)lo;
}
__device__ __forceinline__ float readlane_f(float v, int l) {
    return __int_as_float(__builtin_amdgcn_readlane(__float_as_int(v), l));
}
// Exact replacement for: RN(inter / max(uni,1e-8f)) > 0.5f  (bit-equivalent)
__device__ __forceinline__ bool iou_gt_half(float inter, float uni) {
    double b = (double)fmaxf(uni, 1e-8f);
    return (double)inter * 2.0 > b * 0x1.000001p0;
}
__device__ __forceinline__ float parse_imgf(int raw) {
    return (raw > 0 && raw < 1000000) ? (float)raw : __int_as_float(raw);
}

// ---------------- fused: decode + bitonic sort + wave0 greedy NMS + top-K ----------------
__global__ __launch_bounds__(NTHREADS)
void roiheads_fused(const float* __restrict__ class_logit,
                    const float* __restrict__ box_reg,
                    const float* __restrict__ proposal,
                    const int* __restrict__ image_shape_p,
                    float* __restrict__ out)
{
#pragma clang fp contract(off)
    __shared__ unsigned long long skey[N_PROP];     // 16 KB sort keys
    __shared__ float blo_n[N_PROP], bhi_n[N_PROP];  // boxes, original index order
    __shared__ float slo[N_PROP], shi[N_PROP];      // boxes in sorted order
    __shared__ unsigned char keep[N_PROP];
    __shared__ float clo[KEPT_MAX], chi[KEPT_MAX];  // kept boxes so far (NMS)
    __shared__ unsigned long long kmask[NBLK64];
    __shared__ int sh_nvalid;

    const int tid = threadIdx.x;
    const int lane = tid & 63;
    const int wid = tid >> 6;
    const int img = blockIdx.x >> 1;
    const int cls = blockIdx.x & 1;                 // fg class index-1
    const float imgf = parse_imgf(image_shape_p[0]);

    if (tid == 0) sh_nvalid = 0;

    const int p0 = (wid << 7) | (lane << 1);        // == 2*tid, wave-contiguous spans
    const int p1 = p0 | 1;
    const unsigned long long below = (1ull << lane) - 1ull;

    // ---- decode items p0,p1 directly into register sort keys ----
    // (identical fp sequence to reference; boxes parked in LDS by original index)
    unsigned long long r0 = 0, r1 = 0;
#pragma unroll
    for (int e = 0; e < 2; ++e) {
        const int n = p0 + e;
        const size_t g = (size_t)img * N_PROP + n;
        const float* lg = class_logit + g * C_CLS;
        float l0 = lg[0], l1 = lg[1], l2 = lg[2];
        float mx = fmaxf(l0, fmaxf(l1, l2));
        float e0 = (float)exp((double)(l0 - mx));
        float e1 = (float)exp((double)(l1 - mx));
        float e2 = (float)exp((double)(l2 - mx));
        float denom = (e0 + e1) + e2;
        float score = ((cls == 0) ? e1 : e2) / denom;

        const float* dr = box_reg + g * (2 * C_CLS) + 2 * (cls + 1);
        float dx = dr[0];                           // / WX == 1
        float dw = fminf(dr[1], 4.0f);              // / WW == 1, clamp 4
        const float* pp = proposal + g * 2;
        float pA = pp[0], pB = pp[1];
        float w = pB - pA;
        float ctr = pA + 0.5f * w;
        float tt = dx * w;
        float pc = tt + ctr;
        float pw = (float)exp((double)dw) * w;
        float half = 0.5f * pw;
        float lo = pc - half;
        float hi = pc + half;
        lo = fminf(fmaxf(lo, 0.0f), imgf);
        hi = fminf(fmaxf(hi, 0.0f), imgf);
        bool valid = ((hi - lo) >= 10.0f) && (score >= 0.05f);
        float ms = valid ? score : -1e9f;
        blo_n[n] = lo;
        bhi_n[n] = hi;
        unsigned int uu = __float_as_uint(ms);
        unsigned int enc = (uu & 0x80000000u) ? ~uu : (uu | 0x80000000u); // order-preserving
        unsigned long long key = ((unsigned long long)enc << 32) |
                                 (unsigned long long)(0xFFFFFFFFu - (unsigned int)n); // idx asc on ties
        if (e == 0) r0 = key; else r1 = key;
    }

    // ---- full hybrid reg/LDS bitonic sort over 2048 (descending) ----
    auto pass_inreg = [&](int k, int j) {
        if (j == 1) {
            bool desc = ((p0 & k) == 0);
            bool sw = desc ? (r0 < r1) : (r0 > r1);
            if (sw) { unsigned long long t = r0; r0 = r1; r1 = t; }
        } else {
            int lx = j >> 1;
            unsigned long long o0 = shfl_xor_u64(r0, lx);
            unsigned long long o1 = shfl_xor_u64(r1, lx);
            bool desc = ((p0 & k) == 0);
            bool lower = ((p0 & j) == 0);
            bool takeMax = (lower == desc);
            r0 = takeMax ? (r0 > o0 ? r0 : o0) : (r0 < o0 ? r0 : o0);
            r1 = takeMax ? (r1 > o1 ? r1 : o1) : (r1 < o1 ? r1 : o1);
        }
    };

    for (int k = 2; k <= 128; k <<= 1)
        for (int j = k >> 1; j >= 1; j >>= 1)
            pass_inreg(k, j);

    for (int k = 256; k <= N_PROP; k <<= 1) {
        skey[p0] = r0; skey[p1] = r1;
        __syncthreads();
        for (int j = k >> 1; j >= 128; j >>= 1) {
            int i = ((tid & ~(j - 1)) << 1) | (tid & (j - 1));
            int part = i | j;
            unsigned long long a = skey[i], b = skey[part];
            bool desc_blk = ((i & k) == 0);
            bool sw = desc_blk ? (a < b) : (a > b);
            if (sw) { skey[i] = b; skey[part] = a; }
            __syncthreads();
        }
        r0 = skey[p0]; r1 = skey[p1];
        for (int j = 64; j >= 1; j >>= 1)
            pass_inreg(k, j);
    }
    skey[p0] = r0; skey[p1] = r1;
    __syncthreads();

    // ---- gather sorted boxes from LDS, count valid ----
    for (int i = tid; i < N_PROP; i += NTHREADS) {
        unsigned long long kk = skey[i];
        unsigned int e = (unsigned int)(kk >> 32);
        unsigned int sb = (e & 0x80000000u) ? (e & 0x7FFFFFFFu) : ~e;
        float s = __uint_as_float(sb);
        unsigned int n = 0xFFFFFFFFu - (unsigned int)(kk & 0xFFFFFFFFull);
        slo[i] = blo_n[n];
        shi[i] = bhi_n[n];
        keep[i] = 0;
        bool v = (s > -5e8f);    // keep0 = s > 0.5*NEG  (valid items sort first)
        unsigned long long mb = __ballot(v);
        if (lane == 0) atomicAdd(&sh_nvalid, __popcll(mb));
    }
    __syncthreads();

    const int nvalid = sh_nvalid;

    // ---- greedy NMS on wave 0 only: zero barriers, chunk-sequential ----
    // Candidate p is kept iff it overlaps no earlier kept box. Earlier-chunk
    // kept boxes: direct test vs clo/chi (broadcast LDS reads). Same-chunk:
    // serial greedy on the ballot mask; iteration count == kept-in-chunk
    // (killed candidates leave the mask before being visited). Decisions are
    // bit-identical to the reference scan (float + is commutative; same
    // iou_gt_half predicate). Stop once tk >= K_OUT: outputs only use the
    // first 100 kept when >=100 exist (kept scores sort above all NEG).
    if (wid == 0) {
        int tk = 0;
        for (int c0 = 0; c0 < nvalid && tk < K_OUT; c0 += 64) {
            const int p = c0 + lane;
            const bool in = (p < nvalid);
            float qlo = in ? slo[p] : 0.0f;
            float qhi = in ? shi[p] : 0.0f;
            bool alive = in;
            for (int r = 0; r < tk; ++r) {
                float cl = clo[r], ch = chi[r];            // broadcast reads
                float inter = fmaxf(fminf(ch, qhi) - fmaxf(cl, qlo), 0.0f);
                float uni = (ch - cl) + (qhi - qlo) - inter;
                alive = alive && !iou_gt_half(inter, uni);
                if (__ballot(alive) == 0ull) break;
            }
            unsigned long long A = __ballot(alive);
            unsigned long long kept = 0;
            while (A) {
                int c = __builtin_ctzll(A);                // wave-uniform
                unsigned long long bit = 1ull << c;
                kept |= bit;
                float rlo = readlane_f(qlo, c);
                float rhi = readlane_f(qhi, c);
                float inter = fmaxf(fminf(rhi, qhi) - fmaxf(rlo, qlo), 0.0f);
                float uni = (rhi - rlo) + (qhi - qlo) - inter;
                bool kill = (lane > c) && iou_gt_half(inter, uni);
                A &= ~(__ballot(kill) | bit);
            }
            if ((kept >> lane) & 1ull) {
                keep[p] = 1;
                int rank = tk + __popcll(kept & below);
                clo[rank] = qlo; chi[rank] = qhi;          // wave-sync LDS, no barrier
            }
            tk += __popcll(kept);
        }
    }
    __syncthreads();

    // ---- top-K fill (reproduces lax.top_k tie-breaking exactly) ----
    for (int blk = wid; blk < NBLK64; blk += NWAVES) {
        bool kk = keep[blk * 64 + lane] != 0;
        unsigned long long mb = __ballot(kk);
        if (lane == 0) kmask[blk] = mb;
    }
    __syncthreads();
    {
        float* outp = out + (((size_t)img * 2 + cls) * K_OUT) * 3;
        for (int blk = wid; blk < NBLK64; blk += NWAVES) {
            int kc = 0, nc = 0, nk = 0;
            for (int b = 0; b < NBLK64; ++b) {
                int pc = __popcll(kmask[b]);
                nk += pc;
                if (b < blk) { kc += pc; nc += 64 - pc; }
            }
            if (kc >= K_OUT && nk + nc >= K_OUT && nc >= K_OUT) continue;
            int p = blk * 64 + lane;
            unsigned long long mb = kmask[blk];
            bool k = (mb >> lane) & 1ull;
            int rk = kc + __popcll(mb & below);
            int rn = nc + __popcll((~mb) & below);
            if (k) {
                if (rk < K_OUT) {
                    unsigned long long kk2 = skey[p];
                    unsigned int e = (unsigned int)(kk2 >> 32);
                    unsigned int sb = (e & 0x80000000u) ? (e & 0x7FFFFFFFu) : ~e;
                    outp[rk * 3 + 0] = slo[p];
                    outp[rk * 3 + 1] = shi[p];
                    outp[rk * 3 + 2] = __uint_as_float(sb);
                }
            } else {
                int oi = nk + rn;
                if (oi < K_OUT) {
                    outp[oi * 3 + 0] = slo[p];
                    outp[oi * 3 + 1] = shi[p];
                    outp[oi * 3 + 2] = -1e9f;
                }
            }
        }
    }
}

extern "C" void kernel_launch(void* const* d_in, const int* in_sizes, int n_in,
                              void* d_out, int out_size, void* d_ws, size_t ws_size,
                              hipStream_t stream) {
    const float* class_logit = (const float*)d_in[0];
    const float* box_reg     = (const float*)d_in[1];
    const float* prop        = (const float*)d_in[2];
    const int*   image_shape = (const int*)d_in[3];
    float* out = (float*)d_out;
    (void)d_ws; (void)ws_size;   // workspace unused — everything lives in LDS

    roiheads_fused<<<dim3(B_IMG * 2), dim3(NTHREADS), 0, stream>>>(
        class_logit, box_reg, prop, image_shape, out);
}

// Round 5
// 109.489 us; speedup vs baseline: 5.7691x; 2.4022x over previous
//
#include <hip/hip_runtime.h>
#include <math.h>

#define B_IMG 16
#define N_PROP 2048
#define C_CLS 3
#define K_OUT 100
#define NTHREADS 1024
#define NWAVES (NTHREADS / 64)
#define NBLK64 (N_PROP / 64)

// Phase budget (R3 ablation, per block): decode ~3us, sort ~12.7us,
// NMS+gather ~24.5us, topK ~1.5us. R4 lesson: wave0-serial NMS with a
// ballot-break LDS chain = 145us disaster; compaction (R1) keeps chunk
// count ~7. This version = R1 NMS structure + cheaper per-chunk apparatus:
// fast-path f32 IoU (exact double fallback), single-round filter
// (2 cands/thread), candidate prefetch over the resolve barriers.

__device__ __forceinline__ unsigned long long shfl_xor_u64(unsigned long long v, int lx) {
    unsigned int lo = (unsigned int)__shfl_xor((int)(unsigned int)(v & 0xffffffffull), lx, 64);
    unsigned int hi = (unsigned int)__shfl_xor((int)(unsigned int)(v >> 32), lx, 64);
    return ((unsigned long long)hi << 32) | (unsigned long long)lo;
}
__device__ __forceinline__ float readlane_f(float v, int l) {
    return __int_as_float(__builtin_amdgcn_readlane(__float_as_int(v), l));
}
__device__ __forceinline__ unsigned long long readlane_u64(unsigned long long v, int l) {
    unsigned int lo = (unsigned int)__builtin_amdgcn_readlane((int)(unsigned int)(v & 0xffffffffull), l);
    unsigned int hi = (unsigned int)__builtin_amdgcn_readlane((int)(unsigned int)(v >> 32), l);
    return ((unsigned long long)hi << 32) | (unsigned long long)lo;
}
// Bit-exact replacement for: RN(inter / max(uni,1e-8f)) > 0.5f.
// Original exact form: 2a > b*(1+2^-24) evaluated in double (b*(1+2^-24)
// exact: 24+25=49<53 bits). Fast path: lhs=2a exact in f32;
//   lhs <= b            -> false  (b <= b_hat)
//   lhs >  RN(b*(1+2^-22)) -> true (RN(x)>=x*(1-2^-24) so product >= b*(1+2^-24))
// narrow band -> original double evaluation. b >= 1e-8 is normal, no subnormal
// rounding caveats; doubling never rounds. All paths equal the original.
__device__ __forceinline__ bool iou_gt_half(float inter, float uni) {
    float b = fmaxf(uni, 1e-8f);
    float lhs = 2.0f * inter;
    if (__builtin_expect(lhs > b, 0)) {
        if (lhs > b * 0x1.000004p0f) return true;
        double bb = (double)b;
        return (double)inter * 2.0 > bb * 0x1.000001p0;
    }
    return false;
}
__device__ __forceinline__ float parse_imgf(int raw) {
    return (raw > 0 && raw < 1000000) ? (float)raw : __int_as_float(raw);
}

// ---------------- fused: decode + bitonic sort + compaction NMS + top-K ----------------
__global__ __launch_bounds__(NTHREADS)
void roiheads_fused(const float* __restrict__ class_logit,
                    const float* __restrict__ box_reg,
                    const float* __restrict__ proposal,
                    const int* __restrict__ image_shape_p,
                    float* __restrict__ out)
{
#pragma clang fp contract(off)
    __shared__ unsigned long long skey[N_PROP];     // 16 KB sort keys
    __shared__ float blo_n[N_PROP], bhi_n[N_PROP];  // boxes, original index order
    __shared__ float slo[N_PROP], shi[N_PROP];      // boxes in sorted order
    __shared__ unsigned char keep[N_PROP];
    __shared__ unsigned short alv[2][N_PROP];       // alive (undecided) sorted positions
    __shared__ float2 cbox[64];                     // current chunk's kept boxes
    __shared__ unsigned long long sup[64];          // chunk suppression matrix rows
    __shared__ unsigned long long kmask[NBLK64];
    __shared__ int wsum[NWAVES];                    // packed (cntA<<16)|cntB per wave
    __shared__ int sh_nvalid;

    const int tid = threadIdx.x;
    const int lane = tid & 63;
    const int wid = tid >> 6;
    const int img = blockIdx.x >> 1;
    const int cls = blockIdx.x & 1;                 // fg class index-1
    const float imgf = parse_imgf(image_shape_p[0]);

    if (tid == 0) sh_nvalid = 0;

    const int p0 = (wid << 7) | (lane << 1);        // == 2*tid, wave-contiguous spans
    const int p1 = p0 | 1;
    const unsigned long long below = (1ull << lane) - 1ull;

    // ---- decode items p0,p1 directly into register sort keys ----
    // (identical fp sequence to reference; boxes parked in LDS by original index)
    unsigned long long r0 = 0, r1 = 0;
#pragma unroll
    for (int e = 0; e < 2; ++e) {
        const int n = p0 + e;
        const size_t g = (size_t)img * N_PROP + n;
        const float* lg = class_logit + g * C_CLS;
        float l0 = lg[0], l1 = lg[1], l2 = lg[2];
        float mx = fmaxf(l0, fmaxf(l1, l2));
        float e0 = (float)exp((double)(l0 - mx));
        float e1 = (float)exp((double)(l1 - mx));
        float e2 = (float)exp((double)(l2 - mx));
        float denom = (e0 + e1) + e2;
        float score = ((cls == 0) ? e1 : e2) / denom;

        const float* dr = box_reg + g * (2 * C_CLS) + 2 * (cls + 1);
        float dx = dr[0];                           // / WX == 1
        float dw = fminf(dr[1], 4.0f);              // / WW == 1, clamp 4
        const float* pp = proposal + g * 2;
        float pA = pp[0], pB = pp[1];
        float w = pB - pA;
        float ctr = pA + 0.5f * w;
        float tt = dx * w;
        float pc = tt + ctr;
        float pw = (float)exp((double)dw) * w;
        float half = 0.5f * pw;
        float lo = pc - half;
        float hi = pc + half;
        lo = fminf(fmaxf(lo, 0.0f), imgf);
        hi = fminf(fmaxf(hi, 0.0f), imgf);
        bool valid = ((hi - lo) >= 10.0f) && (score >= 0.05f);
        float ms = valid ? score : -1e9f;
        blo_n[n] = lo;
        bhi_n[n] = hi;
        unsigned int uu = __float_as_uint(ms);
        unsigned int enc = (uu & 0x80000000u) ? ~uu : (uu | 0x80000000u); // order-preserving
        unsigned long long key = ((unsigned long long)enc << 32) |
                                 (unsigned long long)(0xFFFFFFFFu - (unsigned int)n); // idx asc on ties
        if (e == 0) r0 = key; else r1 = key;
    }

    // ---- full hybrid reg/LDS bitonic sort over 2048 (descending) ----
    auto pass_inreg = [&](int k, int j) {
        if (j == 1) {
            bool desc = ((p0 & k) == 0);
            bool sw = desc ? (r0 < r1) : (r0 > r1);
            if (sw) { unsigned long long t = r0; r0 = r1; r1 = t; }
        } else {
            int lx = j >> 1;
            unsigned long long o0 = shfl_xor_u64(r0, lx);
            unsigned long long o1 = shfl_xor_u64(r1, lx);
            bool desc = ((p0 & k) == 0);
            bool lower = ((p0 & j) == 0);
            bool takeMax = (lower == desc);
            r0 = takeMax ? (r0 > o0 ? r0 : o0) : (r0 < o0 ? r0 : o0);
            r1 = takeMax ? (r1 > o1 ? r1 : o1) : (r1 < o1 ? r1 : o1);
        }
    };

    for (int k = 2; k <= 128; k <<= 1)
        for (int j = k >> 1; j >= 1; j >>= 1)
            pass_inreg(k, j);

    for (int k = 256; k <= N_PROP; k <<= 1) {
        skey[p0] = r0; skey[p1] = r1;
        __syncthreads();
        for (int j = k >> 1; j >= 128; j >>= 1) {
            int i = ((tid & ~(j - 1)) << 1) | (tid & (j - 1));
            int part = i | j;
            unsigned long long a = skey[i], b = skey[part];
            bool desc_blk = ((i & k) == 0);
            bool sw = desc_blk ? (a < b) : (a > b);
            if (sw) { skey[i] = b; skey[part] = a; }
            __syncthreads();
        }
        r0 = skey[p0]; r1 = skey[p1];
        for (int j = 64; j >= 1; j >>= 1)
            pass_inreg(k, j);
    }
    skey[p0] = r0; skey[p1] = r1;
    __syncthreads();

    // ---- gather sorted boxes from LDS, count valid, init alive list ----
    for (int i = tid; i < N_PROP; i += NTHREADS) {
        unsigned long long kk = skey[i];
        unsigned int e = (unsigned int)(kk >> 32);
        unsigned int sb = (e & 0x80000000u) ? (e & 0x7FFFFFFFu) : ~e;
        float s = __uint_as_float(sb);
        unsigned int n = 0xFFFFFFFFu - (unsigned int)(kk & 0xFFFFFFFFull);
        slo[i] = blo_n[n];
        shi[i] = bhi_n[n];
        keep[i] = 0;
        bool v = (s > -5e8f);    // keep0 = s > 0.5*NEG  (valid items sort first)
        unsigned long long mb = __ballot(v);
        if (lane == 0) atomicAdd(&sh_nvalid, __popcll(mb));
        alv[0][i] = (unsigned short)i;
    }
    __syncthreads();

    int na = sh_nvalid;
    int cur = 0;
    int tk = 0;

    // ---- greedy NMS: 64-chunk + compaction (R1 structure, cheaper apparatus) ----
    while (na > 0) {
        const int m = (na < 64) ? na : 64;

        // chunk boxes: every wave holds the full chunk in its lanes
        unsigned short cp = alv[cur][lane];
        bool cin = (lane < m);
        float qloc = cin ? slo[cp] : 0.0f;
        float qhic = cin ? shi[cp] : 0.0f;

        // 64x64 suppression matrix: 4 rows per wave
#pragma unroll
        for (int rr4 = 0; rr4 < 4; ++rr4) {
            int rr = (wid << 2) | rr4;
            unsigned long long row = 0;
            if (rr < m) {
                unsigned short rp = alv[cur][rr];     // wave-uniform
                float rlo = slo[rp], rhi = shi[rp];   // broadcast LDS reads
                float inter = fmaxf(fminf(rhi, qhic) - fmaxf(rlo, qloc), 0.0f);
                float uni = (rhi - rlo) + (qhic - qloc) - inter;
                bool kill = cin && (lane > rr) && iou_gt_half(inter, uni);
                row = __ballot(kill);
            }
            if (lane == 0) sup[rr] = row;
        }

        // prefetch this chunk's filter candidates (2 per thread) BEFORE the
        // resolve barriers -- alv[cur]/slo/shi are stable within the chunk,
        // and these loads hide the serial-resolve latency.
        const int iA = 64 + tid;
        const int iB = 64 + NTHREADS + tid;
        const bool vA = (iA < na);
        const bool vB = (iB < na);
        unsigned short qqA = vA ? alv[cur][iA] : 0;
        unsigned short qqB = vB ? alv[cur][iB] : 0;
        float qAlo = vA ? slo[qqA] : 0.0f;
        float qAhi = vA ? shi[qqA] : 0.0f;
        float qBlo = vB ? slo[qqB] : 0.0f;
        float qBhi = vB ? shi[qqB] : 0.0f;
        __syncthreads();

        // greedy mask resolve (redundant on all threads; keeps all waves busy)
        unsigned long long rw = sup[lane];
        unsigned long long A = (m >= 64) ? ~0ull : ((1ull << m) - 1ull);
        unsigned long long kept = 0;
        while (A) {
            int c = __builtin_ctzll(A);
            kept |= (1ull << c);
            A &= ~(readlane_u64(rw, c) | (1ull << c));
        }
        const int cnt = __popcll(kept);

        if (wid == 0) {
            bool alive = cin && ((kept >> lane) & 1ull);
            if (alive) {
                keep[cp] = 1;
                int rank = __popcll(kept & below);
                cbox[rank] = make_float2(qloc, qhic);
            }
        }
        __syncthreads();
        tk += cnt;
        if (tk >= K_OUT) break;   // later decisions provably unused

        // single-round filter: 2 candidates per thread vs this chunk's kept
        bool survA = vA, survB = vB;
        {
            float qAw = qAhi - qAlo;
            float qBw = qBhi - qBlo;
            bool dA = false, dB = false;
#pragma unroll 4
            for (int r = 0; r < cnt; ++r) {
                float2 cb = cbox[r];                  // broadcast b64 read
                float interA = fmaxf(fminf(qAhi, cb.y) - fmaxf(qAlo, cb.x), 0.0f);
                float uniA = qAw + (cb.y - cb.x) - interA;
                dA |= iou_gt_half(interA, uniA);
                float interB = fmaxf(fminf(qBhi, cb.y) - fmaxf(qBlo, cb.x), 0.0f);
                float uniB = qBw + (cb.y - cb.x) - interB;
                dB |= iou_gt_half(interB, uniB);
            }
            survA = vA && !dA;
            survB = vB && !dB;
        }
        unsigned long long mbA = __ballot(survA);
        unsigned long long mbB = __ballot(survB);
        if (lane == 0) wsum[wid] = (__popcll(mbA) << 16) | __popcll(mbB);
        __syncthreads();
        int offA = 0, offB = 0, totA = 0, totB = 0;
#pragma unroll
        for (int w2 = 0; w2 < NWAVES; ++w2) {
            unsigned pk = (unsigned)wsum[w2];
            int ca = (int)(pk >> 16), cb2 = (int)(pk & 0xffffu);
            if (w2 < wid) { offA += ca; offB += cb2; }
            totA += ca; totB += cb2;
        }
        // order-preserving scatter: all A-set survivors precede B-set survivors
        if (survA) alv[cur ^ 1][offA + __popcll(mbA & below)] = qqA;
        if (survB) alv[cur ^ 1][totA + offB + __popcll(mbB & below)] = qqB;
        __syncthreads();
        na = totA + totB;
        cur ^= 1;
    }

    // ---- top-K fill (reproduces lax.top_k tie-breaking exactly) ----
    for (int blk = wid; blk < NBLK64; blk += NWAVES) {
        bool kk = keep[blk * 64 + lane] != 0;
        unsigned long long mb = __ballot(kk);
        if (lane == 0) kmask[blk] = mb;
    }
    __syncthreads();
    {
        float* outp = out + (((size_t)img * 2 + cls) * K_OUT) * 3;
        for (int blk = wid; blk < NBLK64; blk += NWAVES) {
            int kc = 0, nc = 0, nk = 0;
            for (int b = 0; b < NBLK64; ++b) {
                int pc = __popcll(kmask[b]);
                nk += pc;
                if (b < blk) { kc += pc; nc += 64 - pc; }
            }
            if (kc >= K_OUT && nk + nc >= K_OUT && nc >= K_OUT) continue;
            int p = blk * 64 + lane;
            unsigned long long mb = kmask[blk];
            bool k = (mb >> lane) & 1ull;
            int rk = kc + __popcll(mb & below);
            int rn = nc + __popcll((~mb) & below);
            if (k) {
                if (rk < K_OUT) {
                    unsigned long long kk2 = skey[p];
                    unsigned int e = (unsigned int)(kk2 >> 32);
                    unsigned int sb = (e & 0x80000000u) ? (e & 0x7FFFFFFFu) : ~e;
                    outp[rk * 3 + 0] = slo[p];
                    outp[rk * 3 + 1] = shi[p];
                    outp[rk * 3 + 2] = __uint_as_float(sb);
                }
            } else {
                int oi = nk + rn;
                if (oi < K_OUT) {
                    outp[oi * 3 + 0] = slo[p];
                    outp[oi * 3 + 1] = shi[p];
                    outp[oi * 3 + 2] = -1e9f;
                }
            }
        }
    }
}

extern "C" void kernel_launch(void* const* d_in, const int* in_sizes, int n_in,
                              void* d_out, int out_size, void* d_ws, size_t ws_size,
                              hipStream_t stream) {
    const float* class_logit = (const float*)d_in[0];
    const float* box_reg     = (const float*)d_in[1];
    const float* prop        = (const float*)d_in[2];
    const int*   image_shape = (const int*)d_in[3];
    float* out = (float*)d_out;
    (void)d_ws; (void)ws_size;   // workspace unused -- everything lives in LDS

    roiheads_fused<<<dim3(B_IMG * 2), dim3(NTHREADS), 0, stream>>>(
        class_logit, box_reg, prop, image_shape, out);
}

// Round 6
// 103.624 us; speedup vs baseline: 6.0956x; 1.0566x over previous
//
#include <hip/hip_runtime.h>
#include <math.h>

#define B_IMG 16
#define N_PROP 2048
#define C_CLS 3
#define K_OUT 100
#define NTHREADS 1024
#define NWAVES (NTHREADS / 64)
#define NBLK64 (N_PROP / 64)

// Phase budget (R3 ablation, per block): decode ~3us, sort ~12.7us,
// NMS+gather ~16-26us, topK ~3us. Lessons: R4 (no compaction, LDS-chained
// resolve) = 29 chunks disaster; R2/R5 (wider chunks / branchy IoU / LDS
// cbox) = apparatus got MORE expensive. This version keeps R1's compaction
// dynamics but runs each chunk register-only: redundant per-wave greedy
// resolve via readlane broadcasts, filter tests folded into the resolve
// iteration (off the dependent chain), 2 barriers/chunk instead of 6,
// no sup-matrix or cbox LDS round-trips. Branchless double IoU (R1's).

__device__ __forceinline__ unsigned long long shfl_xor_u64(unsigned long long v, int lx) {
    unsigned int lo = (unsigned int)__shfl_xor((int)(unsigned int)(v & 0xffffffffull), lx, 64);
    unsigned int hi = (unsigned int)__shfl_xor((int)(unsigned int)(v >> 32), lx, 64);
    return ((unsigned long long)hi << 32) | (unsigned long long)lo;
}
__device__ __forceinline__ float readlane_f(float v, int l) {
    return __int_as_float(__builtin_amdgcn_readlane(__float_as_int(v), l));
}
// Exact replacement for: RN(inter / max(uni,1e-8f)) > 0.5f
// RN(a/b) > 0.5 <=> a/b > 0.5+2^-25 <=> 2a > b*(1+2^-24); b*(1+2^-24) exact in
// double (24+25=49 < 53 bits). Bit-equivalent to the reference decision.
// Branchless: the R5 fast-path branch cost more than the double math
// (any-lane divergence makes every wave take both paths).
__device__ __forceinline__ bool iou_gt_half(float inter, float uni) {
    double b = (double)fmaxf(uni, 1e-8f);
    return (double)inter * 2.0 > b * 0x1.000001p0;
}
__device__ __forceinline__ float parse_imgf(int raw) {
    return (raw > 0 && raw < 1000000) ? (float)raw : __int_as_float(raw);
}

// ---------------- fused: decode + bitonic sort + register-chunk NMS + top-K ----------------
__global__ __launch_bounds__(NTHREADS)
void roiheads_fused(const float* __restrict__ class_logit,
                    const float* __restrict__ box_reg,
                    const float* __restrict__ proposal,
                    const int* __restrict__ image_shape_p,
                    float* __restrict__ out)
{
#pragma clang fp contract(off)
    __shared__ unsigned long long skey[N_PROP];     // 16 KB sort keys
    __shared__ float blo_n[N_PROP], bhi_n[N_PROP];  // boxes, original index order
    __shared__ float slo[N_PROP], shi[N_PROP];      // boxes in sorted order
    __shared__ unsigned char keep[N_PROP];
    __shared__ unsigned short alv[2][N_PROP];       // alive (undecided) sorted positions
    __shared__ unsigned long long kmask[NBLK64];
    __shared__ int wsum[NWAVES];                    // packed (cntA<<16)|cntB per wave
    __shared__ int sh_nvalid;

    const int tid = threadIdx.x;
    const int lane = tid & 63;
    const int wid = tid >> 6;
    const int img = blockIdx.x >> 1;
    const int cls = blockIdx.x & 1;                 // fg class index-1
    const float imgf = parse_imgf(image_shape_p[0]);

    if (tid == 0) sh_nvalid = 0;

    const int p0 = (wid << 7) | (lane << 1);        // == 2*tid, wave-contiguous spans
    const int p1 = p0 | 1;
    const unsigned long long below = (1ull << lane) - 1ull;

    // ---- decode items p0,p1 directly into register sort keys ----
    // (identical fp sequence to reference; boxes parked in LDS by original index)
    unsigned long long r0 = 0, r1 = 0;
#pragma unroll
    for (int e = 0; e < 2; ++e) {
        const int n = p0 + e;
        const size_t g = (size_t)img * N_PROP + n;
        const float* lg = class_logit + g * C_CLS;
        float l0 = lg[0], l1 = lg[1], l2 = lg[2];
        float mx = fmaxf(l0, fmaxf(l1, l2));
        float e0 = (float)exp((double)(l0 - mx));
        float e1 = (float)exp((double)(l1 - mx));
        float e2 = (float)exp((double)(l2 - mx));
        float denom = (e0 + e1) + e2;
        float score = ((cls == 0) ? e1 : e2) / denom;

        const float* dr = box_reg + g * (2 * C_CLS) + 2 * (cls + 1);
        float dx = dr[0];                           // / WX == 1
        float dw = fminf(dr[1], 4.0f);              // / WW == 1, clamp 4
        const float* pp = proposal + g * 2;
        float pA = pp[0], pB = pp[1];
        float w = pB - pA;
        float ctr = pA + 0.5f * w;
        float tt = dx * w;
        float pc = tt + ctr;
        float pw = (float)exp((double)dw) * w;
        float half = 0.5f * pw;
        float lo = pc - half;
        float hi = pc + half;
        lo = fminf(fmaxf(lo, 0.0f), imgf);
        hi = fminf(fmaxf(hi, 0.0f), imgf);
        bool valid = ((hi - lo) >= 10.0f) && (score >= 0.05f);
        float ms = valid ? score : -1e9f;
        blo_n[n] = lo;
        bhi_n[n] = hi;
        unsigned int uu = __float_as_uint(ms);
        unsigned int enc = (uu & 0x80000000u) ? ~uu : (uu | 0x80000000u); // order-preserving
        unsigned long long key = ((unsigned long long)enc << 32) |
                                 (unsigned long long)(0xFFFFFFFFu - (unsigned int)n); // idx asc on ties
        if (e == 0) r0 = key; else r1 = key;
    }

    // ---- full hybrid reg/LDS bitonic sort over 2048 (descending) ----
    auto pass_inreg = [&](int k, int j) {
        if (j == 1) {
            bool desc = ((p0 & k) == 0);
            bool sw = desc ? (r0 < r1) : (r0 > r1);
            if (sw) { unsigned long long t = r0; r0 = r1; r1 = t; }
        } else {
            int lx = j >> 1;
            unsigned long long o0 = shfl_xor_u64(r0, lx);
            unsigned long long o1 = shfl_xor_u64(r1, lx);
            bool desc = ((p0 & k) == 0);
            bool lower = ((p0 & j) == 0);
            bool takeMax = (lower == desc);
            r0 = takeMax ? (r0 > o0 ? r0 : o0) : (r0 < o0 ? r0 : o0);
            r1 = takeMax ? (r1 > o1 ? r1 : o1) : (r1 < o1 ? r1 : o1);
        }
    };

    for (int k = 2; k <= 128; k <<= 1)
        for (int j = k >> 1; j >= 1; j >>= 1)
            pass_inreg(k, j);

    for (int k = 256; k <= N_PROP; k <<= 1) {
        skey[p0] = r0; skey[p1] = r1;
        __syncthreads();
        for (int j = k >> 1; j >= 128; j >>= 1) {
            int i = ((tid & ~(j - 1)) << 1) | (tid & (j - 1));
            int part = i | j;
            unsigned long long a = skey[i], b = skey[part];
            bool desc_blk = ((i & k) == 0);
            bool sw = desc_blk ? (a < b) : (a > b);
            if (sw) { skey[i] = b; skey[part] = a; }
            __syncthreads();
        }
        r0 = skey[p0]; r1 = skey[p1];
        for (int j = 64; j >= 1; j >>= 1)
            pass_inreg(k, j);
    }
    skey[p0] = r0; skey[p1] = r1;
    __syncthreads();

    // ---- gather sorted boxes from LDS, count valid, init alive list ----
    for (int i = tid; i < N_PROP; i += NTHREADS) {
        unsigned long long kk = skey[i];
        unsigned int e = (unsigned int)(kk >> 32);
        unsigned int sb = (e & 0x80000000u) ? (e & 0x7FFFFFFFu) : ~e;
        float s = __uint_as_float(sb);
        unsigned int n = 0xFFFFFFFFu - (unsigned int)(kk & 0xFFFFFFFFull);
        slo[i] = blo_n[n];
        shi[i] = bhi_n[n];
        keep[i] = 0;
        bool v = (s > -5e8f);    // keep0 = s > 0.5*NEG  (valid items sort first)
        unsigned long long mb = __ballot(v);
        if (lane == 0) atomicAdd(&sh_nvalid, __popcll(mb));
        alv[0][i] = (unsigned short)i;
    }
    __syncthreads();

    int na = sh_nvalid;
    int cur = 0;
    int tk = 0;

    // ---- greedy NMS: 64-chunk + compaction, register-only chunk internals ----
    // Every wave holds the chunk's 64 boxes in its lanes (qloc/qhic), so each
    // wave redundantly runs the greedy resolve via readlane broadcasts; the
    // same broadcast box feeds (a) the in-chunk kill ballot (drives A) and
    // (b) this thread's 2 filter candidates (off the dependent chain).
    // Decisions are bit-identical to the reference scan: same chunk
    // boundaries (stable compaction), same greedy order, same IoU predicate
    // (float + commutes in `uni`). 2 barriers per chunk.
    while (na > 0) {
        const int m = (na < 64) ? na : 64;

        unsigned short cp = alv[cur][lane];
        bool cin = (lane < m);
        float qloc = cin ? slo[cp] : 0.0f;
        float qhic = cin ? shi[cp] : 0.0f;

        // filter candidates (2 per thread covers na<=2048); loads issue here,
        // consumed during the resolve -- latency hidden, no barrier needed
        const int iA = 64 + tid;
        const int iB = 64 + NTHREADS + tid;
        const bool vA = (iA < na);
        const bool vB = (iB < na);
        unsigned short qqA = vA ? alv[cur][iA] : 0;
        unsigned short qqB = vB ? alv[cur][iB] : 0;
        float qAlo = vA ? slo[qqA] : 0.0f;
        float qAhi = vA ? shi[qqA] : 0.0f;
        float qBlo = vB ? slo[qqB] : 0.0f;
        float qBhi = vB ? shi[qqB] : 0.0f;
        const float qAw = qAhi - qAlo;
        const float qBw = qBhi - qBlo;

        unsigned long long A = (m >= 64) ? ~0ull : ((1ull << m) - 1ull);
        unsigned long long kept = 0;
        bool deadA = false, deadB = false;
        while (A) {
            int c = __builtin_ctzll(A);                // wave-uniform
            unsigned long long bit = 1ull << c;
            kept |= bit;
            float cl = readlane_f(qloc, c);
            float ch = readlane_f(qhic, c);
            float cw = ch - cl;
            // in-chunk kill (drives the A-mask chain)
            float inter = fmaxf(fminf(ch, qhic) - fmaxf(cl, qloc), 0.0f);
            float uni = cw + (qhic - qloc) - inter;
            bool kill = (lane > c) && iou_gt_half(inter, uni);
            // filter accumulation for the 2 out-of-chunk candidates (ILP)
            float inA = fmaxf(fminf(qAhi, ch) - fmaxf(qAlo, cl), 0.0f);
            float unA = qAw + cw - inA;
            deadA |= iou_gt_half(inA, unA);
            float inB = fmaxf(fminf(qBhi, ch) - fmaxf(qBlo, cl), 0.0f);
            float unB = qBw + cw - inB;
            deadB |= iou_gt_half(inB, unB);
            A &= ~(__ballot(kill) | bit);
        }
        const int cnt = __popcll(kept);

        if (wid == 0) {
            if (cin && ((kept >> lane) & 1ull)) keep[cp] = 1;
        }
        tk += cnt;
        if (tk >= K_OUT) break;   // later decisions provably unused
                                  // (post-loop __syncthreads orders keep[] writes)

        bool survA = vA && !deadA;
        bool survB = vB && !deadB;
        unsigned long long mbA = __ballot(survA);
        unsigned long long mbB = __ballot(survB);
        if (lane == 0) wsum[wid] = (__popcll(mbA) << 16) | (int)__popcll(mbB);
        __syncthreads();
        int offA = 0, offB = 0, totA = 0, totB = 0;
#pragma unroll
        for (int w2 = 0; w2 < NWAVES; ++w2) {
            unsigned pk = (unsigned)wsum[w2];
            int ca = (int)(pk >> 16), cb2 = (int)(pk & 0xffffu);
            if (w2 < wid) { offA += ca; offB += cb2; }
            totA += ca; totB += cb2;
        }
        // order-preserving scatter: all A-set survivors precede B-set survivors
        if (survA) alv[cur ^ 1][offA + __popcll(mbA & below)] = qqA;
        if (survB) alv[cur ^ 1][totA + offB + __popcll(mbB & below)] = qqB;
        __syncthreads();
        na = totA + totB;
        cur ^= 1;
    }
    __syncthreads();

    // ---- top-K fill (reproduces lax.top_k tie-breaking exactly) ----
    for (int blk = wid; blk < NBLK64; blk += NWAVES) {
        bool kk = keep[blk * 64 + lane] != 0;
        unsigned long long mb = __ballot(kk);
        if (lane == 0) kmask[blk] = mb;
    }
    __syncthreads();
    {
        float* outp = out + (((size_t)img * 2 + cls) * K_OUT) * 3;
        for (int blk = wid; blk < NBLK64; blk += NWAVES) {
            int kc = 0, nc = 0, nk = 0;
            for (int b = 0; b < NBLK64; ++b) {
                int pc = __popcll(kmask[b]);
                nk += pc;
                if (b < blk) { kc += pc; nc += 64 - pc; }
            }
            if (kc >= K_OUT && nk + nc >= K_OUT && nc >= K_OUT) continue;
            int p = blk * 64 + lane;
            unsigned long long mb = kmask[blk];
            bool k = (mb >> lane) & 1ull;
            int rk = kc + __popcll(mb & below);
            int rn = nc + __popcll((~mb) & below);
            if (k) {
                if (rk < K_OUT) {
                    unsigned long long kk2 = skey[p];
                    unsigned int e = (unsigned int)(kk2 >> 32);
                    unsigned int sb = (e & 0x80000000u) ? (e & 0x7FFFFFFFu) : ~e;
                    outp[rk * 3 + 0] = slo[p];
                    outp[rk * 3 + 1] = shi[p];
                    outp[rk * 3 + 2] = __uint_as_float(sb);
                }
            } else {
                int oi = nk + rn;
                if (oi < K_OUT) {
                    outp[oi * 3 + 0] = slo[p];
                    outp[oi * 3 + 1] = shi[p];
                    outp[oi * 3 + 2] = -1e9f;
                }
            }
        }
    }
}

extern "C" void kernel_launch(void* const* d_in, const int* in_sizes, int n_in,
                              void* d_out, int out_size, void* d_ws, size_t ws_size,
                              hipStream_t stream) {
    const float* class_logit = (const float*)d_in[0];
    const float* box_reg     = (const float*)d_in[1];
    const float* prop        = (const float*)d_in[2];
    const int*   image_shape = (const int*)d_in[3];
    float* out = (float*)d_out;
    (void)d_ws; (void)ws_size;   // workspace unused -- everything lives in LDS

    roiheads_fused<<<dim3(B_IMG * 2), dim3(NTHREADS), 0, stream>>>(
        class_logit, box_reg, prop, image_shape, out);
}